// Round 8
// baseline (187.162 us; speedup 1.0000x reference)
//
#include <hip/hip_runtime.h>
#include <hip/hip_bf16.h>

typedef __bf16 bf16_t;
typedef __attribute__((ext_vector_type(8))) __bf16 bf16x8;
typedef __attribute__((ext_vector_type(4))) __bf16 bf16x4;
typedef __attribute__((ext_vector_type(4))) float f32x4;
typedef __attribute__((ext_vector_type(16))) float f32x16;

#define MFMA32(A,B,C) __builtin_amdgcn_mfma_f32_32x32x16_bf16((A),(B),(C),0,0,0)

#define BATCH 2
#define SEQ 2048
#define DMODEL 1024
#define NHEAD 16
#define HDIM 64
#define MROWS (BATCH * SEQ)   // 4096

// async 16B global->LDS. Global addr may be per-lane; LDS dest is
// wave-uniform base + lane*16.
__device__ __forceinline__ void async16(const bf16_t* g, bf16_t* l) {
    __builtin_amdgcn_global_load_lds(
        (const __attribute__((address_space(1))) unsigned int*)g,
        (__attribute__((address_space(3))) unsigned int*)l, 16, 0, 0);
}

// swizzled fragment loads: physical chunk = logical chunk ^ f(row)
// rows of 32 elems (64B, 4 chunks): f(row) = (row>>1)&3
__device__ __forceinline__ bf16x8 ldsA32(const bf16_t* base, int row, int chunk) {
    return *(const bf16x8*)&base[row * 32 + ((chunk ^ ((row >> 1) & 3)) << 3)];
}
// rows of 64 elems (128B, 8 chunks): f(row) = row&7
__device__ __forceinline__ bf16x8 ldsA64(const bf16_t* base, int row, int chunk) {
    return *(const bf16x8*)&base[row * 64 + ((chunk ^ (row & 7)) << 3)];
}

// pack two fp32 -> 2 bf16 in one u32 (RNE)
__device__ __forceinline__ unsigned pk(float a, float b) {
    union { unsigned u; bf16_t h[2]; } t;
    t.h[0] = (bf16_t)a;
    t.h[1] = (bf16_t)b;
    return t.u;
}

// ---------------------------------------------------------------------------
// Fused splits. Blocks 0..4095: x -> bf16. Blocks 4096..8191: weights (hi
// only) with head-reorder (z<3: row r'=h*64+d takes old 16*d+h; Wq scaled
// 0.125*log2e so attention can use exp2); z==3 (Wo): identity order.
// ---------------------------------------------------------------------------
__global__ void split_kernel(const float* __restrict__ x, const float* __restrict__ Wq,
                             const float* __restrict__ Wk, const float* __restrict__ Wv,
                             const float* __restrict__ Wo, bf16_t* __restrict__ xh,
                             bf16_t* __restrict__ wh) {
    int blk = blockIdx.x;
    if (blk < 4096) {
        int i = blk * 256 + threadIdx.x;
        f32x4 v = ((const f32x4*)x)[i];
        bf16x4 h;
#pragma unroll
        for (int c = 0; c < 4; ++c) h[c] = (bf16_t)v[c];
        ((bf16x4*)xh)[i] = h;
        return;
    }
    int e = blk - 4096;
    int z = e >> 10;
    int i = (e & 1023) * 256 + threadIdx.x;       // 0..262143
    const float* src = (z == 0) ? Wq : (z == 1) ? Wk : (z == 2) ? Wv : Wo;
    const float scale = (z == 0) ? 0.125f * 1.44269504088896f : 1.0f;
    int row = i >> 8, col4 = i & 255;
    int r_src;
    if (z < 3) {
        int h = row >> 6, d = row & 63;
        r_src = 16 * d + h;
    } else {
        r_src = row;
    }
    f32x4 v = ((const f32x4*)src)[r_src * 256 + col4];
    bf16x4 h4;
#pragma unroll
    for (int c = 0; c < 4; ++c) h4[c] = (bf16_t)(v[c] * scale);
    ((bf16x4*)(wh + (size_t)z * DMODEL * DMODEL))[i] = h4;
}

// ---------------------------------------------------------------------------
// QKV GEMM C = A * B^T, single-product bf16, 32x32x16 MFMA.
// 128x128x32 tile, 4 waves (2x2 of 64x64 = 2x2 MFMA tiles each).
// Double-buffered LDS, DMA one iteration ahead -> 1 barrier/iter.
// A/B frag: [row=ln32][k = hl*8+j] per 16-k chunk (in-situ verified).
// C/D: col=ln32, row=(r&3)+8*(r>>2)+4*hl  [m101-verified].
// ---------------------------------------------------------------------------
__global__ __launch_bounds__(256)
void gemm_qkv_kernel(const bf16_t* __restrict__ Ah, const bf16_t* __restrict__ Bh0,
                     bf16_t* __restrict__ Coh0, int M, int Nn, int Kk) {
    __shared__ __align__(16) bf16_t smem[2][8192];  // 32 KB: A[128x32] | B[128x32]

    const int z = blockIdx.z;
    const bf16_t* Bh = Bh0 + (size_t)z * Nn * Kk;
    const int m0 = blockIdx.y * 128, n0 = blockIdx.x * 128;
    const int tid = threadIdx.x;
    const int wave = tid >> 6, lane = tid & 63;
    const int ln32 = lane & 31, hl = lane >> 5;
    const int wr = wave >> 1, wc = wave & 1;

    // staging: 16 issues (A:8, B:8), 4 per wave
    const bf16_t* g_ptr[4];
    int l_off[4];
#pragma unroll
    for (int q = 0; q < 4; ++q) {
        int e = wave * 4 + q;
        int a = e >> 3, u = e & 7;
        int C = u * 64 + lane;
        int r = C >> 2, p = C & 3;
        int c = p ^ ((r >> 1) & 3);           // inverse swizzle on global side
        g_ptr[q] = (a == 0 ? Ah + (size_t)(m0 + r) * Kk
                           : Bh + (size_t)(n0 + r) * Kk) + c * 8;
        l_off[q] = a * 4096 + u * 512;
    }

    f32x16 acc[2][2];
#pragma unroll
    for (int mt = 0; mt < 2; ++mt)
#pragma unroll
        for (int nt = 0; nt < 2; ++nt)
#pragma unroll
            for (int r = 0; r < 16; ++r) acc[mt][nt][r] = 0.0f;

#pragma unroll
    for (int q = 0; q < 4; ++q)
        async16(g_ptr[q], &smem[0][l_off[q]]);

    const int NIT = Kk / 32;
    for (int j = 0; j < NIT; ++j) {
        __syncthreads();
        if (j + 1 < NIT) {
#pragma unroll
            for (int q = 0; q < 4; ++q)
                async16(g_ptr[q] + (j + 1) * 32, &smem[(j + 1) & 1][l_off[q]]);
        }
        const bf16_t* cur = smem[j & 1];

        bf16x8 a[2][2], b[2][2];
#pragma unroll
        for (int t = 0; t < 2; ++t)
#pragma unroll
            for (int kc = 0; kc < 2; ++kc) {
                a[t][kc] = ldsA32(cur, wr * 64 + t * 32 + ln32, kc * 2 + hl);
                b[t][kc] = ldsA32(cur + 4096, wc * 64 + t * 32 + ln32, kc * 2 + hl);
            }
#pragma unroll
        for (int mt = 0; mt < 2; ++mt)
#pragma unroll
            for (int nt = 0; nt < 2; ++nt)
#pragma unroll
                for (int kc = 0; kc < 2; ++kc)
                    acc[mt][nt] = MFMA32(a[mt][kc], b[nt][kc], acc[mt][nt]);
    }

    // epilogue: 32x32 C/D layout
#pragma unroll
    for (int mt = 0; mt < 2; ++mt)
#pragma unroll
        for (int nt = 0; nt < 2; ++nt)
#pragma unroll
            for (int r = 0; r < 16; ++r) {
                int gm = m0 + wr * 64 + mt * 32 + (r & 3) + 8 * (r >> 2) + 4 * hl;
                int gn = n0 + wc * 64 + nt * 32 + ln32;
                Coh0[(size_t)z * M * Nn + (size_t)gm * Nn + gn] =
                    (bf16_t)acc[mt][nt][r];
            }
}

// ---------------------------------------------------------------------------
// Out-proj GEMM: C = A * B^T, single-product bf16, 32x32x16 MFMA, fp32 out.
// 64x128x32 tile -> grid 512. Wave = 32x64 (1x2 MFMA tiles).
// Double-buffered, 1 barrier/iter.
// ---------------------------------------------------------------------------
__global__ __launch_bounds__(256)
void gemm_out_kernel(const bf16_t* __restrict__ Ah, const bf16_t* __restrict__ Bh,
                     float* __restrict__ Cf, int M, int Nn, int Kk) {
    __shared__ __align__(16) bf16_t smem[2][6144];  // 24 KB: A 64x32 | B 128x32

    const int m0 = blockIdx.y * 64, n0 = blockIdx.x * 128;
    const int tid = threadIdx.x;
    const int wave = tid >> 6, lane = tid & 63;
    const int ln32 = lane & 31, hl = lane >> 5;
    const int wr = wave >> 1, wc = wave & 1;

    // 12 issues (A:4, B:8), 3 per wave
    const bf16_t* g_ptr[3];
    int l_off[3];
#pragma unroll
    for (int q = 0; q < 3; ++q) {
        int e = wave * 3 + q;
        const bf16_t* arr;
        int u, rowbase, lb;
        if (e < 4) { arr = Ah; u = e;     rowbase = m0; lb = 0; }
        else       { arr = Bh; u = e - 4; rowbase = n0; lb = 2048; }
        int r = u * 16 + (lane >> 2), p = lane & 3;
        int c = p ^ ((r >> 1) & 3);
        g_ptr[q] = arr + (size_t)(rowbase + r) * Kk + c * 8;
        l_off[q] = lb + u * 512;
    }

    f32x16 acc[2];
#pragma unroll
    for (int nt = 0; nt < 2; ++nt)
#pragma unroll
        for (int r = 0; r < 16; ++r) acc[nt][r] = 0.0f;

#pragma unroll
    for (int q = 0; q < 3; ++q)
        async16(g_ptr[q], &smem[0][l_off[q]]);

    const int NIT = Kk / 32;
    for (int j = 0; j < NIT; ++j) {
        __syncthreads();
        if (j + 1 < NIT) {
#pragma unroll
            for (int q = 0; q < 3; ++q)
                async16(g_ptr[q] + (j + 1) * 32, &smem[(j + 1) & 1][l_off[q]]);
        }
        const bf16_t* cur = smem[j & 1];

        bf16x8 a[2], b[2][2];
#pragma unroll
        for (int kc = 0; kc < 2; ++kc) {
            a[kc] = ldsA32(cur, wr * 32 + ln32, kc * 2 + hl);
#pragma unroll
            for (int nt = 0; nt < 2; ++nt)
                b[nt][kc] = ldsA32(cur + 2048, wc * 64 + nt * 32 + ln32, kc * 2 + hl);
        }
#pragma unroll
        for (int nt = 0; nt < 2; ++nt)
#pragma unroll
            for (int kc = 0; kc < 2; ++kc)
                acc[nt] = MFMA32(a[kc], b[nt][kc], acc[nt]);
    }

#pragma unroll
    for (int nt = 0; nt < 2; ++nt)
#pragma unroll
        for (int r = 0; r < 16; ++r) {
            int gm = m0 + wr * 32 + (r & 3) + 8 * (r >> 2) + 4 * hl;
            int gn = n0 + wc * 64 + nt * 32 + ln32;
            Cf[(size_t)gm * Nn + gn] = acc[nt][r];
        }
}

// ---------------------------------------------------------------------------
// V transpose: concat layout [b][n][h*64+d] -> [bh][d][n].
// ---------------------------------------------------------------------------
__global__ __launch_bounds__(256)
void vtrans_kernel(const bf16_t* __restrict__ Vn, bf16_t* __restrict__ Vt) {
    __shared__ bf16_t t[64][66];
    const int bh = blockIdx.y;
    const int b = bh >> 4, h = bh & 15;
    const int n0 = blockIdx.x * 64;
    const int tid = threadIdx.x;
#pragma unroll
    for (int it = 0; it < 2; ++it) {
        int c = it * 256 + tid;
        int r = c >> 3, p = c & 7;
        *(bf16x8*)&t[r][p * 8] =
            *(const bf16x8*)&Vn[((size_t)(b * SEQ + n0 + r)) * DMODEL + h * HDIM + p * 8];
    }
    __syncthreads();
#pragma unroll
    for (int it = 0; it < 2; ++it) {
        int c = it * 256 + tid;
        int d = c >> 3, p = c & 7;
        bf16x8 v;
#pragma unroll
        for (int e = 0; e < 8; ++e) v[e] = t[p * 8 + e][d];
        *(bf16x8*)&Vt[((size_t)(bh * HDIM + d)) * SEQ + n0 + p * 8] = v;
    }
}

// ---------------------------------------------------------------------------
// Flash attention (round-6 structure): 512 threads = 2 wave-groups of 4
// waves; group g owns keys [g*1024, g*1024+1024) with its own double-
// buffered 64-key K/V tiles. VALU row-sum (measured faster than ones-MFMA).
// 32x32x16 MFMA; S^T = Kh*Qh^T; O^T = Vh^T*P. exp2 (log2e folded in Wq).
// ---------------------------------------------------------------------------
__global__ __launch_bounds__(512, 4)
void attn_kernel(const bf16_t* __restrict__ Qh, const bf16_t* __restrict__ Kh,
                 const bf16_t* __restrict__ Vt, bf16_t* __restrict__ Ch) {
    __shared__ __align__(16) bf16_t smem[2][2][8192];  // [group][buf][K 4096|V 4096]

    const int bh = blockIdx.y;
    const int b = bh >> 4, h = bh & 15;
    const int q0 = blockIdx.x * 128;
    const int tid = threadIdx.x;
    const int g = tid >> 8;                    // wave-group 0/1
    const int wv = (tid >> 6) & 3;             // wave within group
    const int lane = tid & 63;
    const int ln32 = lane & 31, hl = lane >> 5;

    // Q fragments (both groups load the same q-rows): B[q=ln32][k=hl*8+j]
    bf16x8 qfh[4];
    {
        size_t qrow = ((size_t)(b * SEQ + q0 + wv * 32 + ln32)) * DMODEL +
                      h * HDIM + hl * 8;
#pragma unroll
        for (int c = 0; c < 4; ++c)
            qfh[c] = *(const bf16x8*)&Qh[qrow + c * 16];
    }

    // staging: per group 16 issues (K:8, V:8), 4 per wave; keys g*1024 + j*64
    bf16_t* gsm = &smem[g][0][0];
    const bf16_t* g_base[4];
    int l_off[4];
    size_t g_step[4];
#pragma unroll
    for (int q = 0; q < 4; ++q) {
        int e = wv * 4 + q;
        int a = e >> 3, u = e & 7;
        int r = u * 8 + (lane >> 3), p = lane & 7;
        int c = p ^ (r & 7);                   // inverse swizzle on global side
        if (a == 0) {                          // K tile [64 keys][64 el]
            g_base[q] = Kh + ((size_t)(b * SEQ + g * 1024 + r)) * DMODEL +
                        h * HDIM + c * 8;
            l_off[q] = u * 512;
            g_step[q] = (size_t)64 * DMODEL;
        } else {                               // V^T tile [64 d][64 keys]
            g_base[q] = Vt + ((size_t)(bh * HDIM + r)) * SEQ + g * 1024 + c * 8;
            l_off[q] = 4096 + u * 512;
            g_step[q] = 64;
        }
    }

    f32x16 o[2];
#pragma unroll
    for (int dt = 0; dt < 2; ++dt)
#pragma unroll
        for (int r = 0; r < 16; ++r) o[dt][r] = 0.0f;
    float rs = 0.0f;

#pragma unroll
    for (int q = 0; q < 4; ++q)
        async16(g_base[q], gsm + l_off[q]);

    for (int j = 0; j < 16; ++j) {
        __syncthreads();  // buf j&1 DMA landed; reads of buf (j+1)&1 done
        if (j < 15) {
#pragma unroll
            for (int q = 0; q < 4; ++q)
                async16(g_base[q] + (j + 1) * g_step[q],
                        gsm + ((j + 1) & 1) * 8192 + l_off[q]);
        }
        const bf16_t* Kc = gsm + (j & 1) * 8192;
        const bf16_t* Vc = Kc + 4096;

        bf16x8 pfrag[4];
#pragma unroll
        for (int kt = 0; kt < 2; ++kt) {
            // S^T subtile: D[key = kt*32 + (r&3)+8*(r>>2)+4*hl][q = ln32]
            f32x16 st;
#pragma unroll
            for (int r = 0; r < 16; ++r) st[r] = 0.0f;
#pragma unroll
            for (int c = 0; c < 4; ++c) {
                bf16x8 kh = ldsA64(Kc, kt * 32 + ln32, 2 * c + hl);
                st = MFMA32(kh, qfh[c], st);
            }
            float pexp[16];
#pragma unroll
            for (int r = 0; r < 16; ++r) {
                pexp[r] = __builtin_amdgcn_exp2f(st[r]);
                rs += pexp[r];
            }
            // C->B layout: pack bf16 pairs, quad swap with lane^32
#pragma unroll
            for (int s1 = 0; s1 < 2; ++s1) {
                unsigned lo01 = pk(pexp[8 * s1 + 0], pexp[8 * s1 + 1]);
                unsigned lo23 = pk(pexp[8 * s1 + 2], pexp[8 * s1 + 3]);
                unsigned hi01 = pk(pexp[8 * s1 + 4], pexp[8 * s1 + 5]);
                unsigned hi23 = pk(pexp[8 * s1 + 6], pexp[8 * s1 + 7]);
                unsigned sa = hl ? lo01 : hi01;
                unsigned sb = hl ? lo23 : hi23;
                unsigned ra = (unsigned)__shfl_xor((int)sa, 32);
                unsigned rb = (unsigned)__shfl_xor((int)sb, 32);
                union { bf16x8 v; unsigned u[4]; } outv;
                outv.u[0] = hl ? ra : lo01;
                outv.u[1] = hl ? rb : lo23;
                outv.u[2] = hl ? hi01 : ra;
                outv.u[3] = hl ? hi23 : rb;
                pfrag[kt * 2 + s1] = outv.v;
            }
        }
        // O^T += V^T * P over these 64 keys
#pragma unroll
        for (int s = 0; s < 4; ++s) {
            bf16x8 va0 = ldsA64(Vc, ln32, 2 * s + hl);
            bf16x8 va1 = ldsA64(Vc, 32 + ln32, 2 * s + hl);
            o[0] = MFMA32(va0, pfrag[s], o[0]);
            o[1] = MFMA32(va1, pfrag[s], o[1]);
        }
    }

    rs += __shfl_xor(rs, 32);  // full group-sum per q-row

    // ---- combine the two groups' partials (additive) ----
    __syncthreads();                                 // (A) j-loop reads done
    float* cbuf = (float*)smem;                      // 64 d x 128 q f32
    float* rbuf = cbuf + 8192;                       // 128 row sums
    if (g == 1) {
#pragma unroll
        for (int dt = 0; dt < 2; ++dt)
#pragma unroll
            for (int r = 0; r < 16; ++r) {
                int d = dt * 32 + (r & 3) + 8 * (r >> 2) + 4 * hl;
                cbuf[d * 128 + wv * 32 + ln32] = o[dt][r];
            }
        if (hl == 0) rbuf[wv * 32 + ln32] = rs;
    }
    __syncthreads();                                 // (B)
    float inv = 0.0f;
    if (g == 0) {
#pragma unroll
        for (int dt = 0; dt < 2; ++dt)
#pragma unroll
            for (int r = 0; r < 16; ++r) {
                int d = dt * 32 + (r & 3) + 8 * (r >> 2) + 4 * hl;
                o[dt][r] += cbuf[d * 128 + wv * 32 + ln32];
            }
        inv = 1.0f / (rs + rbuf[wv * 32 + ln32]);
    }
    __syncthreads();                                 // (C) combine reads done
    float* fbuf = (float*)smem;                      // [dh][wave][32q][33]
    if (g == 0) {
#pragma unroll
        for (int dh = 0; dh < 2; ++dh)
#pragma unroll
            for (int r = 0; r < 16; ++r) {
                int d_loc = (r & 3) + 8 * (r >> 2) + 4 * hl;
                fbuf[dh * 4224 + wv * 1056 + ln32 * 33 + d_loc] = o[dh][r] * inv;
            }
    }
    __syncthreads();                                 // (D)
    // all 8 waves write: wave id = (dh, w)
    {
        int gw = tid >> 6;                           // 0..7
        int dh = gw >> 2, w = gw & 3;
#pragma unroll
        for (int qq = 0; qq < 16; ++qq) {
            int qrow = hl * 16 + qq;
            float v = fbuf[dh * 4224 + w * 1056 + qrow * 33 + ln32];
            size_t gidx = ((size_t)(b * SEQ + q0 + w * 32 + qrow)) * DMODEL +
                          h * HDIM + dh * 32 + ln32;
            Ch[gidx] = (bf16_t)v;
        }
    }
}

// ---------------------------------------------------------------------------
extern "C" void kernel_launch(void* const* d_in, const int* in_sizes, int n_in,
                              void* d_out, int out_size, void* d_ws, size_t ws_size,
                              hipStream_t stream) {
    const float* x  = (const float*)d_in[0];
    const float* Wq = (const float*)d_in[1];
    const float* Wk = (const float*)d_in[2];
    const float* Wv = (const float*)d_in[3];
    const float* Wo = (const float*)d_in[4];
    float* out = (float*)d_out;

    char* ws = (char*)d_ws;
    size_t off = 0;
    auto alloc = [&](size_t bytes) -> bf16_t* {
        bf16_t* p = (bf16_t*)(ws + off);
        off += (bytes + 255) & ~(size_t)255;
        return p;
    };
    const size_t XE = (size_t)MROWS * DMODEL;      // 4,194,304
    const size_t WE = (size_t)DMODEL * DMODEL;     // 1,048,576

    bf16_t* xh  = alloc(XE * 2);
    bf16_t* wh  = alloc(4 * WE * 2);   // q,k,v,o (q/k/v row-reordered, q scaled)
    bf16_t* qnh = alloc(3 * XE * 2);   // Q,K,V in concat layout (bf16)
    bf16_t* vth = alloc(XE * 2);       // V^T per head
    bf16_t* ch  = alloc(XE * 2);       // attn output
    (void)ws_size; (void)in_sizes; (void)n_in; (void)out_size;

    // 1. fused splits (hi only)
    split_kernel<<<8192, 256, 0, stream>>>(x, Wq, Wk, Wv, Wo, xh, wh);

    // 2. QKV projections, single-product bf16, MFMA32, outputs head-ordered
    gemm_qkv_kernel<<<dim3(DMODEL / 128, MROWS / 128, 3), 256, 0, stream>>>(
        xh, wh, qnh, MROWS, DMODEL, DMODEL);

    // 3. V transpose
    vtrans_kernel<<<dim3(SEQ / 64, BATCH * NHEAD), 256, 0, stream>>>(qnh + 2 * XE, vth);

    // 4. flash attention (split-K wave groups) -> concat (bf16)
    attn_kernel<<<dim3(SEQ / 128, BATCH * NHEAD), 512, 0, stream>>>(
        qnh, qnh + XE, vth, ch);

    // 5. output projection, single-product, MFMA32 -> fp32 d_out
    gemm_out_kernel<<<dim3(DMODEL / 128, MROWS / 64), 256, 0, stream>>>(
        ch, wh + 3 * WE, out, MROWS, DMODEL, DMODEL);
}

// Round 9
// 185.794 us; speedup vs baseline: 1.0074x; 1.0074x over previous
//
#include <hip/hip_runtime.h>
#include <hip/hip_bf16.h>

typedef __bf16 bf16_t;
typedef __attribute__((ext_vector_type(8))) __bf16 bf16x8;
typedef __attribute__((ext_vector_type(4))) __bf16 bf16x4;
typedef __attribute__((ext_vector_type(4))) float f32x4;
typedef __attribute__((ext_vector_type(16))) float f32x16;

#define MFMA32(A,B,C) __builtin_amdgcn_mfma_f32_32x32x16_bf16((A),(B),(C),0,0,0)

#define BATCH 2
#define SEQ 2048
#define DMODEL 1024
#define NHEAD 16
#define HDIM 64
#define MROWS (BATCH * SEQ)   // 4096

// async 16B global->LDS. Global addr may be per-lane; LDS dest is
// wave-uniform base + lane*16.
__device__ __forceinline__ void async16(const bf16_t* g, bf16_t* l) {
    __builtin_amdgcn_global_load_lds(
        (const __attribute__((address_space(1))) unsigned int*)g,
        (__attribute__((address_space(3))) unsigned int*)l, 16, 0, 0);
}

// swizzled fragment loads: physical chunk = logical chunk ^ f(row)
// rows of 32 elems (64B, 4 chunks): f(row) = (row>>1)&3
__device__ __forceinline__ bf16x8 ldsA32(const bf16_t* base, int row, int chunk) {
    return *(const bf16x8*)&base[row * 32 + ((chunk ^ ((row >> 1) & 3)) << 3)];
}
// rows of 64 elems (128B, 8 chunks): f(row) = row&7
__device__ __forceinline__ bf16x8 ldsA64(const bf16_t* base, int row, int chunk) {
    return *(const bf16x8*)&base[row * 64 + ((chunk ^ (row & 7)) << 3)];
}

// pack two fp32 -> 2 bf16 in one u32 (RNE)
__device__ __forceinline__ unsigned pk(float a, float b) {
    union { unsigned u; bf16_t h[2]; } t;
    t.h[0] = (bf16_t)a;
    t.h[1] = (bf16_t)b;
    return t.u;
}

// ---------------------------------------------------------------------------
// Fused splits. Blocks 0..4095: x -> bf16. Blocks 4096..8191: weights (hi
// only) with head-reorder (z<3: row r'=h*64+d takes old 16*d+h; Wq scaled
// 0.125*log2e so attention can use exp2); z==3 (Wo): identity order.
// ---------------------------------------------------------------------------
__global__ void split_kernel(const float* __restrict__ x, const float* __restrict__ Wq,
                             const float* __restrict__ Wk, const float* __restrict__ Wv,
                             const float* __restrict__ Wo, bf16_t* __restrict__ xh,
                             bf16_t* __restrict__ wh) {
    int blk = blockIdx.x;
    if (blk < 4096) {
        int i = blk * 256 + threadIdx.x;
        f32x4 v = ((const f32x4*)x)[i];
        bf16x4 h;
#pragma unroll
        for (int c = 0; c < 4; ++c) h[c] = (bf16_t)v[c];
        ((bf16x4*)xh)[i] = h;
        return;
    }
    int e = blk - 4096;
    int z = e >> 10;
    int i = (e & 1023) * 256 + threadIdx.x;       // 0..262143
    const float* src = (z == 0) ? Wq : (z == 1) ? Wk : (z == 2) ? Wv : Wo;
    const float scale = (z == 0) ? 0.125f * 1.44269504088896f : 1.0f;
    int row = i >> 8, col4 = i & 255;
    int r_src;
    if (z < 3) {
        int h = row >> 6, d = row & 63;
        r_src = 16 * d + h;
    } else {
        r_src = row;
    }
    f32x4 v = ((const f32x4*)src)[r_src * 256 + col4];
    bf16x4 h4;
#pragma unroll
    for (int c = 0; c < 4; ++c) h4[c] = (bf16_t)(v[c] * scale);
    ((bf16x4*)(wh + (size_t)z * DMODEL * DMODEL))[i] = h4;
}

// ---------------------------------------------------------------------------
// QKV GEMM C = A * B^T, single-product bf16, 32x32x16 MFMA.
// 128x128x32 tile, 4 waves. Double-buffered, 1 barrier/iter.
// 1D grid 768 with XCD swizzle: id = 8*((z*4+m0g)*8 + n0i) + (m0i&7)
// -> XCD (id%8) sees a fixed set of 4 A row-slabs (L2-resident) for all
// z/n0; weights stream through L2 once per XCD.
// ---------------------------------------------------------------------------
__global__ __launch_bounds__(256)
void gemm_qkv_kernel(const bf16_t* __restrict__ Ah, const bf16_t* __restrict__ Bh0,
                     bf16_t* __restrict__ Coh0, int M, int Nn, int Kk) {
    __shared__ __align__(16) bf16_t smem[2][8192];  // 32 KB: A[128x32] | B[128x32]

    const int id = blockIdx.x;
    const int xcd = id & 7;
    const int t = id >> 3;          // 0..95
    const int n0i = t & 7;
    const int u = t >> 3;           // 0..11
    const int z = u >> 2;
    const int m0g = u & 3;
    const int m0 = (m0g * 8 + xcd) * 128;
    const int n0 = n0i * 128;

    const bf16_t* Bh = Bh0 + (size_t)z * Nn * Kk;
    const int tid = threadIdx.x;
    const int wave = tid >> 6, lane = tid & 63;
    const int ln32 = lane & 31, hl = lane >> 5;
    const int wr = wave >> 1, wc = wave & 1;

    // staging: 16 issues (A:8, B:8), 4 per wave
    const bf16_t* g_ptr[4];
    int l_off[4];
#pragma unroll
    for (int q = 0; q < 4; ++q) {
        int e = wave * 4 + q;
        int a = e >> 3, uu = e & 7;
        int C = uu * 64 + lane;
        int r = C >> 2, p = C & 3;
        int c = p ^ ((r >> 1) & 3);           // inverse swizzle on global side
        g_ptr[q] = (a == 0 ? Ah + (size_t)(m0 + r) * Kk
                           : Bh + (size_t)(n0 + r) * Kk) + c * 8;
        l_off[q] = a * 4096 + uu * 512;
    }

    f32x16 acc[2][2];
#pragma unroll
    for (int mt = 0; mt < 2; ++mt)
#pragma unroll
        for (int nt = 0; nt < 2; ++nt)
#pragma unroll
            for (int r = 0; r < 16; ++r) acc[mt][nt][r] = 0.0f;

#pragma unroll
    for (int q = 0; q < 4; ++q)
        async16(g_ptr[q], &smem[0][l_off[q]]);

    const int NIT = Kk / 32;
    for (int j = 0; j < NIT; ++j) {
        __syncthreads();
        if (j + 1 < NIT) {
#pragma unroll
            for (int q = 0; q < 4; ++q)
                async16(g_ptr[q] + (j + 1) * 32, &smem[(j + 1) & 1][l_off[q]]);
        }
        const bf16_t* cur = smem[j & 1];

        bf16x8 a[2][2], b[2][2];
#pragma unroll
        for (int tt = 0; tt < 2; ++tt)
#pragma unroll
            for (int kc = 0; kc < 2; ++kc) {
                a[tt][kc] = ldsA32(cur, wr * 64 + tt * 32 + ln32, kc * 2 + hl);
                b[tt][kc] = ldsA32(cur + 4096, wc * 64 + tt * 32 + ln32, kc * 2 + hl);
            }
#pragma unroll
        for (int mt = 0; mt < 2; ++mt)
#pragma unroll
            for (int nt = 0; nt < 2; ++nt)
#pragma unroll
                for (int kc = 0; kc < 2; ++kc)
                    acc[mt][nt] = MFMA32(a[mt][kc], b[nt][kc], acc[mt][nt]);
    }

    // epilogue: 32x32 C/D layout: col=ln32, row=(r&3)+8*(r>>2)+4*hl
#pragma unroll
    for (int mt = 0; mt < 2; ++mt)
#pragma unroll
        for (int nt = 0; nt < 2; ++nt)
#pragma unroll
            for (int r = 0; r < 16; ++r) {
                int gm = m0 + wr * 64 + mt * 32 + (r & 3) + 8 * (r >> 2) + 4 * hl;
                int gn = n0 + wc * 64 + nt * 32 + ln32;
                Coh0[(size_t)z * M * Nn + (size_t)gm * Nn + gn] =
                    (bf16_t)acc[mt][nt][r];
            }
}

// ---------------------------------------------------------------------------
// Out-proj GEMM: C = A * B^T, single-product bf16, 32x32x16 MFMA, fp32 out.
// 64x128x32 tile. 1D grid 512, XCD swizzle: id = 8*(m0g*8+n0i)+(m0i&7)
// -> each XCD keeps 8 A row-slabs + full Wo (3 MB) L2-resident.
// ---------------------------------------------------------------------------
__global__ __launch_bounds__(256)
void gemm_out_kernel(const bf16_t* __restrict__ Ah, const bf16_t* __restrict__ Bh,
                     float* __restrict__ Cf, int M, int Nn, int Kk) {
    __shared__ __align__(16) bf16_t smem[2][6144];  // 24 KB: A 64x32 | B 128x32

    const int id = blockIdx.x;
    const int xcd = id & 7;
    const int t = id >> 3;          // 0..63
    const int n0i = t & 7;
    const int m0g = t >> 3;         // 0..7
    const int m0 = (m0g * 8 + xcd) * 64;
    const int n0 = n0i * 128;

    const int tid = threadIdx.x;
    const int wave = tid >> 6, lane = tid & 63;
    const int ln32 = lane & 31, hl = lane >> 5;
    const int wr = wave >> 1, wc = wave & 1;

    // 12 issues (A:4, B:8), 3 per wave
    const bf16_t* g_ptr[3];
    int l_off[3];
#pragma unroll
    for (int q = 0; q < 3; ++q) {
        int e = wave * 3 + q;
        const bf16_t* arr;
        int u, rowbase, lb;
        if (e < 4) { arr = Ah; u = e;     rowbase = m0; lb = 0; }
        else       { arr = Bh; u = e - 4; rowbase = n0; lb = 2048; }
        int r = u * 16 + (lane >> 2), p = lane & 3;
        int c = p ^ ((r >> 1) & 3);
        g_ptr[q] = arr + (size_t)(rowbase + r) * Kk + c * 8;
        l_off[q] = lb + u * 512;
    }

    f32x16 acc[2];
#pragma unroll
    for (int nt = 0; nt < 2; ++nt)
#pragma unroll
        for (int r = 0; r < 16; ++r) acc[nt][r] = 0.0f;

#pragma unroll
    for (int q = 0; q < 3; ++q)
        async16(g_ptr[q], &smem[0][l_off[q]]);

    const int NIT = Kk / 32;
    for (int j = 0; j < NIT; ++j) {
        __syncthreads();
        if (j + 1 < NIT) {
#pragma unroll
            for (int q = 0; q < 3; ++q)
                async16(g_ptr[q] + (j + 1) * 32, &smem[(j + 1) & 1][l_off[q]]);
        }
        const bf16_t* cur = smem[j & 1];

        bf16x8 a[2], b[2][2];
#pragma unroll
        for (int kc = 0; kc < 2; ++kc) {
            a[kc] = ldsA32(cur, wr * 32 + ln32, kc * 2 + hl);
#pragma unroll
            for (int nt = 0; nt < 2; ++nt)
                b[nt][kc] = ldsA32(cur + 2048, wc * 64 + nt * 32 + ln32, kc * 2 + hl);
        }
#pragma unroll
        for (int nt = 0; nt < 2; ++nt)
#pragma unroll
            for (int kc = 0; kc < 2; ++kc)
                acc[nt] = MFMA32(a[kc], b[nt][kc], acc[nt]);
    }

#pragma unroll
    for (int nt = 0; nt < 2; ++nt)
#pragma unroll
        for (int r = 0; r < 16; ++r) {
            int gm = m0 + wr * 32 + (r & 3) + 8 * (r >> 2) + 4 * hl;
            int gn = n0 + wc * 64 + nt * 32 + ln32;
            Cf[(size_t)gm * Nn + gn] = acc[nt][r];
        }
}

// ---------------------------------------------------------------------------
// V transpose: concat layout [b][n][h*64+d] -> [bh][d][n].
// ---------------------------------------------------------------------------
__global__ __launch_bounds__(256)
void vtrans_kernel(const bf16_t* __restrict__ Vn, bf16_t* __restrict__ Vt) {
    __shared__ bf16_t t[64][66];
    const int bh = blockIdx.y;
    const int b = bh >> 4, h = bh & 15;
    const int n0 = blockIdx.x * 64;
    const int tid = threadIdx.x;
#pragma unroll
    for (int it = 0; it < 2; ++it) {
        int c = it * 256 + tid;
        int r = c >> 3, p = c & 7;
        *(bf16x8*)&t[r][p * 8] =
            *(const bf16x8*)&Vn[((size_t)(b * SEQ + n0 + r)) * DMODEL + h * HDIM + p * 8];
    }
    __syncthreads();
#pragma unroll
    for (int it = 0; it < 2; ++it) {
        int c = it * 256 + tid;
        int d = c >> 3, p = c & 7;
        bf16x8 v;
#pragma unroll
        for (int e = 0; e < 8; ++e) v[e] = t[p * 8 + e][d];
        *(bf16x8*)&Vt[((size_t)(bh * HDIM + d)) * SEQ + n0 + p * 8] = v;
    }
}

// ---------------------------------------------------------------------------
// Flash attention: 512 threads = 2 wave-groups of 4 waves; group g owns keys
// [g*1024, g*1024+1024) with its own double-buffered 64-key K/V tiles.
// 1D grid 512 with XCD swizzle: id = 8*((bh>>3)*16 + qtile) + (bh&7)
// -> all 16 q-tiles of a head co-resident on one XCD; 4 heads/XCD = 2 MB
// K+V in its L2, so the 16x K/V re-read hits L2 instead of L3/HBM.
// ---------------------------------------------------------------------------
__global__ __launch_bounds__(512, 4)
void attn_kernel(const bf16_t* __restrict__ Qh, const bf16_t* __restrict__ Kh,
                 const bf16_t* __restrict__ Vt, bf16_t* __restrict__ Ch) {
    __shared__ __align__(16) bf16_t smem[2][2][8192];  // [group][buf][K 4096|V 4096]

    const int id = blockIdx.x;
    const int bh = ((id >> 7) << 3) | (id & 7);   // (id>>3)>>4 * 8 + xcd
    const int qt = (id >> 3) & 15;
    const int b = bh >> 4, h = bh & 15;
    const int q0 = qt * 128;
    const int tid = threadIdx.x;
    const int g = tid >> 8;                    // wave-group 0/1
    const int wv = (tid >> 6) & 3;             // wave within group
    const int lane = tid & 63;
    const int ln32 = lane & 31, hl = lane >> 5;

    // Q fragments (both groups load the same q-rows): B[q=ln32][k=hl*8+j]
    bf16x8 qfh[4];
    {
        size_t qrow = ((size_t)(b * SEQ + q0 + wv * 32 + ln32)) * DMODEL +
                      h * HDIM + hl * 8;
#pragma unroll
        for (int c = 0; c < 4; ++c)
            qfh[c] = *(const bf16x8*)&Qh[qrow + c * 16];
    }

    // staging: per group 16 issues (K:8, V:8), 4 per wave; keys g*1024 + j*64
    bf16_t* gsm = &smem[g][0][0];
    const bf16_t* g_base[4];
    int l_off[4];
    size_t g_step[4];
#pragma unroll
    for (int q = 0; q < 4; ++q) {
        int e = wv * 4 + q;
        int a = e >> 3, u = e & 7;
        int r = u * 8 + (lane >> 3), p = lane & 7;
        int c = p ^ (r & 7);                   // inverse swizzle on global side
        if (a == 0) {                          // K tile [64 keys][64 el]
            g_base[q] = Kh + ((size_t)(b * SEQ + g * 1024 + r)) * DMODEL +
                        h * HDIM + c * 8;
            l_off[q] = u * 512;
            g_step[q] = (size_t)64 * DMODEL;
        } else {                               // V^T tile [64 d][64 keys]
            g_base[q] = Vt + ((size_t)(bh * HDIM + r)) * SEQ + g * 1024 + c * 8;
            l_off[q] = 4096 + u * 512;
            g_step[q] = 64;
        }
    }

    f32x16 o[2];
#pragma unroll
    for (int dt = 0; dt < 2; ++dt)
#pragma unroll
        for (int r = 0; r < 16; ++r) o[dt][r] = 0.0f;
    float rs = 0.0f;

#pragma unroll
    for (int q = 0; q < 4; ++q)
        async16(g_base[q], gsm + l_off[q]);

    for (int j = 0; j < 16; ++j) {
        __syncthreads();  // buf j&1 DMA landed; reads of buf (j+1)&1 done
        if (j < 15) {
#pragma unroll
            for (int q = 0; q < 4; ++q)
                async16(g_base[q] + (j + 1) * g_step[q],
                        gsm + ((j + 1) & 1) * 8192 + l_off[q]);
        }
        const bf16_t* Kc = gsm + (j & 1) * 8192;
        const bf16_t* Vc = Kc + 4096;

        bf16x8 pfrag[4];
#pragma unroll
        for (int kt = 0; kt < 2; ++kt) {
            // S^T subtile: D[key = kt*32 + (r&3)+8*(r>>2)+4*hl][q = ln32]
            f32x16 st;
#pragma unroll
            for (int r = 0; r < 16; ++r) st[r] = 0.0f;
#pragma unroll
            for (int c = 0; c < 4; ++c) {
                bf16x8 kh = ldsA64(Kc, kt * 32 + ln32, 2 * c + hl);
                st = MFMA32(kh, qfh[c], st);
            }
            float pexp[16];
#pragma unroll
            for (int r = 0; r < 16; ++r) {
                pexp[r] = __builtin_amdgcn_exp2f(st[r]);
                rs += pexp[r];
            }
            // C->B layout: pack bf16 pairs, quad swap with lane^32
#pragma unroll
            for (int s1 = 0; s1 < 2; ++s1) {
                unsigned lo01 = pk(pexp[8 * s1 + 0], pexp[8 * s1 + 1]);
                unsigned lo23 = pk(pexp[8 * s1 + 2], pexp[8 * s1 + 3]);
                unsigned hi01 = pk(pexp[8 * s1 + 4], pexp[8 * s1 + 5]);
                unsigned hi23 = pk(pexp[8 * s1 + 6], pexp[8 * s1 + 7]);
                unsigned sa = hl ? lo01 : hi01;
                unsigned sb = hl ? lo23 : hi23;
                unsigned ra = (unsigned)__shfl_xor((int)sa, 32);
                unsigned rb = (unsigned)__shfl_xor((int)sb, 32);
                union { bf16x8 v; unsigned u[4]; } outv;
                outv.u[0] = hl ? ra : lo01;
                outv.u[1] = hl ? rb : lo23;
                outv.u[2] = hl ? hi01 : ra;
                outv.u[3] = hl ? hi23 : rb;
                pfrag[kt * 2 + s1] = outv.v;
            }
        }
        // O^T += V^T * P over these 64 keys
#pragma unroll
        for (int s = 0; s < 4; ++s) {
            bf16x8 va0 = ldsA64(Vc, ln32, 2 * s + hl);
            bf16x8 va1 = ldsA64(Vc, 32 + ln32, 2 * s + hl);
            o[0] = MFMA32(va0, pfrag[s], o[0]);
            o[1] = MFMA32(va1, pfrag[s], o[1]);
        }
    }

    rs += __shfl_xor(rs, 32);  // full group-sum per q-row

    // ---- combine the two groups' partials (additive) ----
    __syncthreads();                                 // (A) j-loop reads done
    float* cbuf = (float*)smem;                      // 64 d x 128 q f32
    float* rbuf = cbuf + 8192;                       // 128 row sums
    if (g == 1) {
#pragma unroll
        for (int dt = 0; dt < 2; ++dt)
#pragma unroll
            for (int r = 0; r < 16; ++r) {
                int d = dt * 32 + (r & 3) + 8 * (r >> 2) + 4 * hl;
                cbuf[d * 128 + wv * 32 + ln32] = o[dt][r];
            }
        if (hl == 0) rbuf[wv * 32 + ln32] = rs;
    }
    __syncthreads();                                 // (B)
    float inv = 0.0f;
    if (g == 0) {
#pragma unroll
        for (int dt = 0; dt < 2; ++dt)
#pragma unroll
            for (int r = 0; r < 16; ++r) {
                int d = dt * 32 + (r & 3) + 8 * (r >> 2) + 4 * hl;
                o[dt][r] += cbuf[d * 128 + wv * 32 + ln32];
            }
        inv = 1.0f / (rs + rbuf[wv * 32 + ln32]);
    }
    __syncthreads();                                 // (C) combine reads done
    float* fbuf = (float*)smem;                      // [dh][wave][32q][33]
    if (g == 0) {
#pragma unroll
        for (int dh = 0; dh < 2; ++dh)
#pragma unroll
            for (int r = 0; r < 16; ++r) {
                int d_loc = (r & 3) + 8 * (r >> 2) + 4 * hl;
                fbuf[dh * 4224 + wv * 1056 + ln32 * 33 + d_loc] = o[dh][r] * inv;
            }
    }
    __syncthreads();                                 // (D)
    // all 8 waves write: wave id = (dh, w)
    {
        int gw = tid >> 6;                           // 0..7
        int dh = gw >> 2, w = gw & 3;
#pragma unroll
        for (int qq = 0; qq < 16; ++qq) {
            int qrow = hl * 16 + qq;
            float v = fbuf[dh * 4224 + w * 1056 + qrow * 33 + ln32];
            size_t gidx = ((size_t)(b * SEQ + q0 + w * 32 + qrow)) * DMODEL +
                          h * HDIM + dh * 32 + ln32;
            Ch[gidx] = (bf16_t)v;
        }
    }
}

// ---------------------------------------------------------------------------
extern "C" void kernel_launch(void* const* d_in, const int* in_sizes, int n_in,
                              void* d_out, int out_size, void* d_ws, size_t ws_size,
                              hipStream_t stream) {
    const float* x  = (const float*)d_in[0];
    const float* Wq = (const float*)d_in[1];
    const float* Wk = (const float*)d_in[2];
    const float* Wv = (const float*)d_in[3];
    const float* Wo = (const float*)d_in[4];
    float* out = (float*)d_out;

    char* ws = (char*)d_ws;
    size_t off = 0;
    auto alloc = [&](size_t bytes) -> bf16_t* {
        bf16_t* p = (bf16_t*)(ws + off);
        off += (bytes + 255) & ~(size_t)255;
        return p;
    };
    const size_t XE = (size_t)MROWS * DMODEL;      // 4,194,304
    const size_t WE = (size_t)DMODEL * DMODEL;     // 1,048,576

    bf16_t* xh  = alloc(XE * 2);
    bf16_t* wh  = alloc(4 * WE * 2);   // q,k,v,o (q/k/v row-reordered, q scaled)
    bf16_t* qnh = alloc(3 * XE * 2);   // Q,K,V in concat layout (bf16)
    bf16_t* vth = alloc(XE * 2);       // V^T per head
    bf16_t* ch  = alloc(XE * 2);       // attn output
    (void)ws_size; (void)in_sizes; (void)n_in; (void)out_size;

    // 1. fused splits (hi only)
    split_kernel<<<8192, 256, 0, stream>>>(x, Wq, Wk, Wv, Wo, xh, wh);

    // 2. QKV projections, single-product bf16, MFMA32, XCD-swizzled 1D grid
    gemm_qkv_kernel<<<768, 256, 0, stream>>>(xh, wh, qnh, MROWS, DMODEL, DMODEL);

    // 3. V transpose
    vtrans_kernel<<<dim3(SEQ / 64, BATCH * NHEAD), 256, 0, stream>>>(qnh + 2 * XE, vth);

    // 4. flash attention (split-K wave groups), XCD-swizzled 1D grid
    attn_kernel<<<512, 512, 0, stream>>>(qnh, qnh + XE, vth, ch);

    // 5. output projection, single-product, MFMA32, XCD-swizzled 1D grid
    gemm_out_kernel<<<512, 256, 0, stream>>>(ch, wh + 3 * WE, out, MROWS, DMODEL, DMODEL);
}

// Round 11
// 180.250 us; speedup vs baseline: 1.0383x; 1.0308x over previous
//
#include <hip/hip_runtime.h>
#include <hip/hip_bf16.h>

typedef __bf16 bf16_t;
typedef __attribute__((ext_vector_type(8))) __bf16 bf16x8;
typedef __attribute__((ext_vector_type(4))) __bf16 bf16x4;
typedef __attribute__((ext_vector_type(4))) float f32x4;
typedef __attribute__((ext_vector_type(16))) float f32x16;

#define MFMA16(A,B,C) __builtin_amdgcn_mfma_f32_16x16x32_bf16((A),(B),(C),0,0,0)
#define MFMA32(A,B,C) __builtin_amdgcn_mfma_f32_32x32x16_bf16((A),(B),(C),0,0,0)

#define BATCH 2
#define SEQ 2048
#define DMODEL 1024
#define NHEAD 16
#define HDIM 64
#define MROWS (BATCH * SEQ)   // 4096

// async 16B global->LDS. Global addr may be per-lane; LDS dest is
// wave-uniform base + lane*16.
__device__ __forceinline__ void async16(const bf16_t* g, bf16_t* l) {
    __builtin_amdgcn_global_load_lds(
        (const __attribute__((address_space(1))) unsigned int*)g,
        (__attribute__((address_space(3))) unsigned int*)l, 16, 0, 0);
}

// swizzled fragment loads: physical chunk = logical chunk ^ f(row)
// rows of 32 elems (64B, 4 chunks): f(row) = (row>>1)&3
__device__ __forceinline__ bf16x8 ldsA32(const bf16_t* base, int row, int chunk) {
    return *(const bf16x8*)&base[row * 32 + ((chunk ^ ((row >> 1) & 3)) << 3)];
}

// pack two fp32 -> 2 bf16 in one u32 (RNE)
__device__ __forceinline__ unsigned pk(float a, float b) {
    union { unsigned u; bf16_t h[2]; } t;
    t.h[0] = (bf16_t)a;
    t.h[1] = (bf16_t)b;
    return t.u;
}

// ---------------------------------------------------------------------------
// Fused splits. Blocks 0..4095: x -> bf16. Blocks 4096..8191: weights (hi
// only) with head-reorder (z<3: row r'=h*64+d takes old 16*d+h; Wq scaled
// 0.125*log2e so attention can use exp2); z==3 (Wo): identity order.
// ---------------------------------------------------------------------------
__global__ void split_kernel(const float* __restrict__ x, const float* __restrict__ Wq,
                             const float* __restrict__ Wk, const float* __restrict__ Wv,
                             const float* __restrict__ Wo, bf16_t* __restrict__ xh,
                             bf16_t* __restrict__ wh) {
    int blk = blockIdx.x;
    if (blk < 4096) {
        int i = blk * 256 + threadIdx.x;
        f32x4 v = ((const f32x4*)x)[i];
        bf16x4 h;
#pragma unroll
        for (int c = 0; c < 4; ++c) h[c] = (bf16_t)v[c];
        ((bf16x4*)xh)[i] = h;
        return;
    }
    int e = blk - 4096;
    int z = e >> 10;
    int i = (e & 1023) * 256 + threadIdx.x;       // 0..262143
    const float* src = (z == 0) ? Wq : (z == 1) ? Wk : (z == 2) ? Wv : Wo;
    const float scale = (z == 0) ? 0.125f * 1.44269504088896f : 1.0f;
    int row = i >> 8, col4 = i & 255;
    int r_src;
    if (z < 3) {
        int h = row >> 6, d = row & 63;
        r_src = 16 * d + h;
    } else {
        r_src = row;
    }
    f32x4 v = ((const f32x4*)src)[r_src * 256 + col4];
    bf16x4 h4;
#pragma unroll
    for (int c = 0; c < 4; ++c) h4[c] = (bf16_t)(v[c] * scale);
    ((bf16x4*)(wh + (size_t)z * DMODEL * DMODEL))[i] = h4;
}

// ---------------------------------------------------------------------------
// QKV GEMM C = A * B^T, single-product bf16, 16x16x32 MFMA (measured faster
// than 32x32 here). 128x128x32 tile, 4 waves, double-buffered, 1 barrier/it.
// 1D grid 768, XCD swizzle. z==2 epilogue writes V^T [bh][d][n] directly
// (fuses the old vtrans kernel; values bit-identical).
// ---------------------------------------------------------------------------
__global__ __launch_bounds__(256)
void gemm_qkv_kernel(const bf16_t* __restrict__ Ah, const bf16_t* __restrict__ Bh0,
                     bf16_t* __restrict__ Coh0, bf16_t* __restrict__ Vt,
                     int M, int Nn, int Kk) {
    __shared__ __align__(16) bf16_t smem[2][8192];  // 32 KB: A[128x32] | B[128x32]

    const int id = blockIdx.x;
    const int xcd = id & 7;
    const int t = id >> 3;          // 0..95
    const int n0i = t & 7;
    const int u = t >> 3;           // 0..11
    const int z = u >> 2;
    const int m0g = u & 3;
    const int m0 = (m0g * 8 + xcd) * 128;
    const int n0 = n0i * 128;

    const bf16_t* Bh = Bh0 + (size_t)z * Nn * Kk;
    const int tid = threadIdx.x;
    const int wave = tid >> 6, lane = tid & 63, lq = lane >> 4, ln = lane & 15;
    const int wr = wave >> 1, wc = wave & 1;

    // staging: 16 issues (A:8, B:8), 4 per wave
    const bf16_t* g_ptr[4];
    int l_off[4];
#pragma unroll
    for (int q = 0; q < 4; ++q) {
        int e = wave * 4 + q;
        int a = e >> 3, uu = e & 7;
        int C = uu * 64 + lane;
        int r = C >> 2, p = C & 3;
        int c = p ^ ((r >> 1) & 3);           // inverse swizzle on global side
        g_ptr[q] = (a == 0 ? Ah + (size_t)(m0 + r) * Kk
                           : Bh + (size_t)(n0 + r) * Kk) + c * 8;
        l_off[q] = a * 4096 + uu * 512;
    }

    f32x4 acc[4][4] = {};

#pragma unroll
    for (int q = 0; q < 4; ++q)
        async16(g_ptr[q], &smem[0][l_off[q]]);

    const int NIT = Kk / 32;
    for (int j = 0; j < NIT; ++j) {
        __syncthreads();
        if (j + 1 < NIT) {
#pragma unroll
            for (int q = 0; q < 4; ++q)
                async16(g_ptr[q] + (j + 1) * 32, &smem[(j + 1) & 1][l_off[q]]);
        }
        const bf16_t* cur = smem[j & 1];

        bf16x8 ah[4], bh[4];
#pragma unroll
        for (int tt = 0; tt < 4; ++tt) {
            ah[tt] = ldsA32(cur, wr * 64 + tt * 16 + ln, lq);
            bh[tt] = ldsA32(cur + 4096, wc * 64 + tt * 16 + ln, lq);
        }
#pragma unroll
        for (int tm = 0; tm < 4; ++tm)
#pragma unroll
            for (int tn = 0; tn < 4; ++tn)
                acc[tm][tn] = MFMA16(ah[tm], bh[tn], acc[tm][tn]);
    }

    // epilogue. 16x16 C/D: col = lane&15, row = (lane>>4)*4 + reg
    if (z != 2) {
#pragma unroll
        for (int tm = 0; tm < 4; ++tm)
#pragma unroll
            for (int tn = 0; tn < 4; ++tn)
#pragma unroll
                for (int p = 0; p < 4; ++p) {
                    int gm = m0 + wr * 64 + tm * 16 + lq * 4 + p;
                    int gn = n0 + wc * 64 + tn * 16 + ln;
                    Coh0[(size_t)z * M * Nn + (size_t)gm * Nn + gn] =
                        (bf16_t)acc[tm][tn][p];
                }
    } else {
        // V^T: [bh][d][SEQ]; gm -> (b, n), gn -> (h, d); 4 consecutive n per frag
#pragma unroll
        for (int tm = 0; tm < 4; ++tm)
#pragma unroll
            for (int tn = 0; tn < 4; ++tn) {
                int gn = n0 + wc * 64 + tn * 16 + ln;
                int hh = gn >> 6, dd = gn & 63;
                int gm0 = m0 + wr * 64 + tm * 16 + lq * 4;
                int bb = gm0 >> 11, nn = gm0 & 2047;
                bf16x4 v4;
#pragma unroll
                for (int p = 0; p < 4; ++p) v4[p] = (bf16_t)acc[tm][tn][p];
                *(bf16x4*)&Vt[(((size_t)(bb * NHEAD + hh)) * HDIM + dd) * SEQ + nn] = v4;
            }
    }
}

// ---------------------------------------------------------------------------
// Out-proj GEMM: C = A * B^T, single-product bf16, 16x16x32 MFMA, fp32 out.
// 64x128x32 tile, 1D grid 512, XCD swizzle. Double-buffered, 1 barrier/iter.
// ---------------------------------------------------------------------------
__global__ __launch_bounds__(256)
void gemm_out_kernel(const bf16_t* __restrict__ Ah, const bf16_t* __restrict__ Bh,
                     float* __restrict__ Cf, int M, int Nn, int Kk) {
    __shared__ __align__(16) bf16_t smem[2][6144];  // 24 KB: A 64x32 | B 128x32

    const int id = blockIdx.x;
    const int xcd = id & 7;
    const int t = id >> 3;          // 0..63
    const int n0i = t & 7;
    const int m0g = t >> 3;         // 0..7
    const int m0 = (m0g * 8 + xcd) * 64;
    const int n0 = n0i * 128;

    const int tid = threadIdx.x;
    const int wave = tid >> 6, lane = tid & 63, lq = lane >> 4, ln = lane & 15;
    const int wr = wave >> 1, wc = wave & 1;

    // 12 issues (A:4, B:8), 3 per wave
    const bf16_t* g_ptr[3];
    int l_off[3];
#pragma unroll
    for (int q = 0; q < 3; ++q) {
        int e = wave * 3 + q;
        const bf16_t* arr;
        int u, rowbase, lb;
        if (e < 4) { arr = Ah; u = e;     rowbase = m0; lb = 0; }
        else       { arr = Bh; u = e - 4; rowbase = n0; lb = 2048; }
        int r = u * 16 + (lane >> 2), p = lane & 3;
        int c = p ^ ((r >> 1) & 3);
        g_ptr[q] = arr + (size_t)(rowbase + r) * Kk + c * 8;
        l_off[q] = lb + u * 512;
    }

    f32x4 acc[2][4] = {};

#pragma unroll
    for (int q = 0; q < 3; ++q)
        async16(g_ptr[q], &smem[0][l_off[q]]);

    const int NIT = Kk / 32;
    for (int j = 0; j < NIT; ++j) {
        __syncthreads();
        if (j + 1 < NIT) {
#pragma unroll
            for (int q = 0; q < 3; ++q)
                async16(g_ptr[q] + (j + 1) * 32, &smem[(j + 1) & 1][l_off[q]]);
        }
        const bf16_t* cur = smem[j & 1];

        bf16x8 ah[2], bh[4];
#pragma unroll
        for (int tt = 0; tt < 2; ++tt)
            ah[tt] = ldsA32(cur, wr * 32 + tt * 16 + ln, lq);
#pragma unroll
        for (int tt = 0; tt < 4; ++tt)
            bh[tt] = ldsA32(cur + 2048, wc * 64 + tt * 16 + ln, lq);
#pragma unroll
        for (int tm = 0; tm < 2; ++tm)
#pragma unroll
            for (int tn = 0; tn < 4; ++tn)
                acc[tm][tn] = MFMA16(ah[tm], bh[tn], acc[tm][tn]);
    }

#pragma unroll
    for (int tm = 0; tm < 2; ++tm)
#pragma unroll
        for (int tn = 0; tn < 4; ++tn)
#pragma unroll
            for (int p = 0; p < 4; ++p) {
                int gm = m0 + wr * 32 + tm * 16 + lq * 4 + p;
                int gn = n0 + wc * 64 + tn * 16 + ln;
                Cf[(size_t)gm * Nn + gn] = acc[tm][tn][p];
            }
}

// ---------------------------------------------------------------------------
// Flash attention: 512 threads = 2 wave-groups of 4 waves; group g owns keys
// [g*1024, g*1024+1024) with its own double-buffered 64-key K/V tiles.
// XCD-swizzled 1D grid 512. Loop-invariant LDS fragment addresses hoisted
// (xc[] swizzle offsets; staging pointers increment instead of j*step).
// ---------------------------------------------------------------------------
__global__ __launch_bounds__(512, 4)
void attn_kernel(const bf16_t* __restrict__ Qh, const bf16_t* __restrict__ Kh,
                 const bf16_t* __restrict__ Vt, bf16_t* __restrict__ Ch) {
    __shared__ __align__(16) bf16_t smem[2][2][8192];  // [group][buf][K 4096|V 4096]

    const int id = blockIdx.x;
    const int bh = ((id >> 7) << 3) | (id & 7);
    const int qt = (id >> 3) & 15;
    const int b = bh >> 4, h = bh & 15;
    const int q0 = qt * 128;
    const int tid = threadIdx.x;
    const int g = tid >> 8;                    // wave-group 0/1
    const int wv = (tid >> 6) & 3;             // wave within group
    const int lane = tid & 63;
    const int ln32 = lane & 31, hl = lane >> 5;

    // Q fragments: B[q=ln32][k=hl*8+j], chained over hd
    bf16x8 qfh[4];
    {
        size_t qrow = ((size_t)(b * SEQ + q0 + wv * 32 + ln32)) * DMODEL +
                      h * HDIM + hl * 8;
#pragma unroll
        for (int c = 0; c < 4; ++c)
            qfh[c] = *(const bf16x8*)&Qh[qrow + c * 16];
    }

    // hoisted fragment-address terms (loop-invariant): rows kt*32+ln32 have
    // row&7 == ln32&7, so the swizzle xor is kt/dt-independent.
    const int xrow = ln32 * 64;
    int xc[4];
#pragma unroll
    for (int c = 0; c < 4; ++c)
        xc[c] = (((2 * c + hl) ^ (ln32 & 7)) << 3) + xrow;

    // staging: per group 16 issues (K:8, V:8), 4 per wave; keys g*1024 + j*64
    bf16_t* gsm = &smem[g][0][0];
    const bf16_t* g_cur[4];
    int l_off[4];
    size_t g_step[4];
#pragma unroll
    for (int q = 0; q < 4; ++q) {
        int e = wv * 4 + q;
        int a = e >> 3, u = e & 7;
        int r = u * 8 + (lane >> 3), p = lane & 7;
        int c = p ^ (r & 7);                   // inverse swizzle on global side
        if (a == 0) {                          // K tile [64 keys][64 el]
            g_cur[q] = Kh + ((size_t)(b * SEQ + g * 1024 + r)) * DMODEL +
                       h * HDIM + c * 8;
            l_off[q] = u * 512;
            g_step[q] = (size_t)64 * DMODEL;
        } else {                               // V^T tile [64 d][64 keys]
            g_cur[q] = Vt + ((size_t)(bh * HDIM + r)) * SEQ + g * 1024 + c * 8;
            l_off[q] = 4096 + u * 512;
            g_step[q] = 64;
        }
    }

    f32x16 o[2];
#pragma unroll
    for (int dt = 0; dt < 2; ++dt)
#pragma unroll
        for (int r = 0; r < 16; ++r) o[dt][r] = 0.0f;
    float rs = 0.0f;

#pragma unroll
    for (int q = 0; q < 4; ++q) {
        async16(g_cur[q], gsm + l_off[q]);
        g_cur[q] += g_step[q];
    }

    for (int j = 0; j < 16; ++j) {
        __syncthreads();  // buf j&1 DMA landed; reads of buf (j+1)&1 done
        if (j < 15) {
#pragma unroll
            for (int q = 0; q < 4; ++q) {
                async16(g_cur[q], gsm + ((j + 1) & 1) * 8192 + l_off[q]);
                g_cur[q] += g_step[q];
            }
        }
        const bf16_t* Kc = gsm + (j & 1) * 8192;
        const bf16_t* Vc = Kc + 4096;

        bf16x8 pfrag[4];
#pragma unroll
        for (int kt = 0; kt < 2; ++kt) {
            // S^T subtile: D[key = kt*32 + (r&3)+8*(r>>2)+4*hl][q = ln32]
            f32x16 st;
#pragma unroll
            for (int r = 0; r < 16; ++r) st[r] = 0.0f;
#pragma unroll
            for (int c = 0; c < 4; ++c) {
                bf16x8 kh = *(const bf16x8*)&Kc[kt * 2048 + xc[c]];
                st = MFMA32(kh, qfh[c], st);
            }
            float pexp[16];
#pragma unroll
            for (int r = 0; r < 16; ++r) {
                pexp[r] = __builtin_amdgcn_exp2f(st[r]);
                rs += pexp[r];
            }
            // C->B layout: pack bf16 pairs, quad swap with lane^32
#pragma unroll
            for (int s1 = 0; s1 < 2; ++s1) {
                unsigned lo01 = pk(pexp[8 * s1 + 0], pexp[8 * s1 + 1]);
                unsigned lo23 = pk(pexp[8 * s1 + 2], pexp[8 * s1 + 3]);
                unsigned hi01 = pk(pexp[8 * s1 + 4], pexp[8 * s1 + 5]);
                unsigned hi23 = pk(pexp[8 * s1 + 6], pexp[8 * s1 + 7]);
                unsigned sa = hl ? lo01 : hi01;
                unsigned sb = hl ? lo23 : hi23;
                unsigned ra = (unsigned)__shfl_xor((int)sa, 32);
                unsigned rb = (unsigned)__shfl_xor((int)sb, 32);
                union { bf16x8 v; unsigned u[4]; } outv;
                outv.u[0] = hl ? ra : lo01;
                outv.u[1] = hl ? rb : lo23;
                outv.u[2] = hl ? hi01 : ra;
                outv.u[3] = hl ? hi23 : rb;
                pfrag[kt * 2 + s1] = outv.v;
            }
        }
        // O^T += V^T * P over these 64 keys
#pragma unroll
        for (int s = 0; s < 4; ++s) {
            bf16x8 va0 = *(const bf16x8*)&Vc[xc[s]];
            bf16x8 va1 = *(const bf16x8*)&Vc[2048 + xc[s]];
            o[0] = MFMA32(va0, pfrag[s], o[0]);
            o[1] = MFMA32(va1, pfrag[s], o[1]);
        }
    }

    rs += __shfl_xor(rs, 32);  // full group-sum per q-row

    // ---- combine the two groups' partials (additive) ----
    __syncthreads();                                 // (A) j-loop reads done
    float* cbuf = (float*)smem;                      // 64 d x 128 q f32
    float* rbuf = cbuf + 8192;                       // 128 row sums
    if (g == 1) {
#pragma unroll
        for (int dt = 0; dt < 2; ++dt)
#pragma unroll
            for (int r = 0; r < 16; ++r) {
                int d = dt * 32 + (r & 3) + 8 * (r >> 2) + 4 * hl;
                cbuf[d * 128 + wv * 32 + ln32] = o[dt][r];
            }
        if (hl == 0) rbuf[wv * 32 + ln32] = rs;
    }
    __syncthreads();                                 // (B)
    float inv = 0.0f;
    if (g == 0) {
#pragma unroll
        for (int dt = 0; dt < 2; ++dt)
#pragma unroll
            for (int r = 0; r < 16; ++r) {
                int d = dt * 32 + (r & 3) + 8 * (r >> 2) + 4 * hl;
                o[dt][r] += cbuf[d * 128 + wv * 32 + ln32];
            }
        inv = 1.0f / (rs + rbuf[wv * 32 + ln32]);
    }
    __syncthreads();                                 // (C) combine reads done
    float* fbuf = (float*)smem;                      // [dh][wave][32q][33]
    if (g == 0) {
#pragma unroll
        for (int dh = 0; dh < 2; ++dh)
#pragma unroll
            for (int r = 0; r < 16; ++r) {
                int d_loc = (r & 3) + 8 * (r >> 2) + 4 * hl;
                fbuf[dh * 4224 + wv * 1056 + ln32 * 33 + d_loc] = o[dh][r] * inv;
            }
    }
    __syncthreads();                                 // (D)
    // all 8 waves write: wave id = (dh, w)
    {
        int gw = tid >> 6;                           // 0..7
        int dh = gw >> 2, w = gw & 3;
#pragma unroll
        for (int qq = 0; qq < 16; ++qq) {
            int qrow = hl * 16 + qq;
            float v = fbuf[dh * 4224 + w * 1056 + qrow * 33 + ln32];
            size_t gidx = ((size_t)(b * SEQ + q0 + w * 32 + qrow)) * DMODEL +
                          h * HDIM + dh * 32 + ln32;
            Ch[gidx] = (bf16_t)v;
        }
    }
}

// ---------------------------------------------------------------------------
extern "C" void kernel_launch(void* const* d_in, const int* in_sizes, int n_in,
                              void* d_out, int out_size, void* d_ws, size_t ws_size,
                              hipStream_t stream) {
    const float* x  = (const float*)d_in[0];
    const float* Wq = (const float*)d_in[1];
    const float* Wk = (const float*)d_in[2];
    const float* Wv = (const float*)d_in[3];
    const float* Wo = (const float*)d_in[4];
    float* out = (float*)d_out;

    char* ws = (char*)d_ws;
    size_t off = 0;
    auto alloc = [&](size_t bytes) -> bf16_t* {
        bf16_t* p = (bf16_t*)(ws + off);
        off += (bytes + 255) & ~(size_t)255;
        return p;
    };
    const size_t XE = (size_t)MROWS * DMODEL;      // 4,194,304
    const size_t WE = (size_t)DMODEL * DMODEL;     // 1,048,576

    bf16_t* xh  = alloc(XE * 2);
    bf16_t* wh  = alloc(4 * WE * 2);   // q,k,v,o (q/k/v row-reordered, q scaled)
    bf16_t* qnh = alloc(3 * XE * 2);   // Q,K in concat layout (z==2 slab unused)
    bf16_t* vth = alloc(XE * 2);       // V^T per head (written by QKV epilogue)
    bf16_t* ch  = alloc(XE * 2);       // attn output
    (void)ws_size; (void)in_sizes; (void)n_in; (void)out_size;

    // 1. fused splits (hi only)
    split_kernel<<<8192, 256, 0, stream>>>(x, Wq, Wk, Wv, Wo, xh, wh);

    // 2. QKV projections (MFMA16) + fused V-transpose epilogue
    gemm_qkv_kernel<<<768, 256, 0, stream>>>(xh, wh, qnh, vth, MROWS, DMODEL, DMODEL);

    // 3. flash attention (split-K wave groups), XCD-swizzled
    attn_kernel<<<512, 512, 0, stream>>>(qnh, qnh + XE, vth, ch);

    // 4. output projection (MFMA16, single-product) -> fp32 d_out
    gemm_out_kernel<<<512, 256, 0, stream>>>(ch, wh + 3 * WE, out, MROWS, DMODEL, DMODEL);
}

// Round 15
// 178.570 us; speedup vs baseline: 1.0481x; 1.0094x over previous
//
#include <hip/hip_runtime.h>
#include <hip/hip_bf16.h>

typedef __bf16 bf16_t;
typedef __attribute__((ext_vector_type(8))) __bf16 bf16x8;
typedef __attribute__((ext_vector_type(4))) __bf16 bf16x4;
typedef __attribute__((ext_vector_type(4))) float f32x4;
typedef __attribute__((ext_vector_type(16))) float f32x16;

#define MFMA16(A,B,C) __builtin_amdgcn_mfma_f32_16x16x32_bf16((A),(B),(C),0,0,0)
#define MFMA32(A,B,C) __builtin_amdgcn_mfma_f32_32x32x16_bf16((A),(B),(C),0,0,0)

#define BATCH 2
#define SEQ 2048
#define DMODEL 1024
#define NHEAD 16
#define HDIM 64
#define MROWS (BATCH * SEQ)   // 4096

// async 16B global->LDS. Global addr may be per-lane; LDS dest is
// wave-uniform base + lane*16.
__device__ __forceinline__ void async16(const bf16_t* g, bf16_t* l) {
    __builtin_amdgcn_global_load_lds(
        (const __attribute__((address_space(1))) unsigned int*)g,
        (__attribute__((address_space(3))) unsigned int*)l, 16, 0, 0);
}

// swizzled fragment loads: physical chunk = logical chunk ^ f(row)
// rows of 32 elems (64B, 4 chunks): f(row) = (row>>1)&3
__device__ __forceinline__ bf16x8 ldsA32(const bf16_t* base, int row, int chunk) {
    return *(const bf16x8*)&base[row * 32 + ((chunk ^ ((row >> 1) & 3)) << 3)];
}

// pack two fp32 -> 2 bf16 in one u32 (RNE)
__device__ __forceinline__ unsigned pk(float a, float b) {
    union { unsigned u; bf16_t h[2]; } t;
    t.h[0] = (bf16_t)a;
    t.h[1] = (bf16_t)b;
    return t.u;
}

// ---------------------------------------------------------------------------
// Fused splits. Blocks 0..4095: x -> bf16. Blocks 4096..8191: weights (hi
// only) with head-reorder (z<3: row r'=h*64+d takes old 16*d+h; Wq scaled
// 0.125*log2e so attention can use exp2); z==3 (Wo): identity order.
// ---------------------------------------------------------------------------
__global__ void split_kernel(const float* __restrict__ x, const float* __restrict__ Wq,
                             const float* __restrict__ Wk, const float* __restrict__ Wv,
                             const float* __restrict__ Wo, bf16_t* __restrict__ xh,
                             bf16_t* __restrict__ wh) {
    int blk = blockIdx.x;
    if (blk < 4096) {
        int i = blk * 256 + threadIdx.x;
        f32x4 v = ((const f32x4*)x)[i];
        bf16x4 h;
#pragma unroll
        for (int c = 0; c < 4; ++c) h[c] = (bf16_t)v[c];
        ((bf16x4*)xh)[i] = h;
        return;
    }
    int e = blk - 4096;
    int z = e >> 10;
    int i = (e & 1023) * 256 + threadIdx.x;       // 0..262143 (WE/4)
    const float* src = (z == 0) ? Wq : (z == 1) ? Wk : (z == 2) ? Wv : Wo;
    const float scale = (z == 0) ? 0.125f * 1.44269504088896f : 1.0f;
    int row = i >> 8, col4 = i & 255;
    int r_src;
    if (z < 3) {
        int h = row >> 6, d = row & 63;
        r_src = 16 * d + h;
    } else {
        r_src = row;
    }
    f32x4 v = ((const f32x4*)src)[r_src * 256 + col4];
    bf16x4 h4;
#pragma unroll
    for (int c = 0; c < 4; ++c) h4[c] = (bf16_t)(v[c] * scale);
    ((bf16x4*)(wh + (size_t)z * DMODEL * DMODEL))[i] = h4;
}

// ---------------------------------------------------------------------------
// QKV GEMM C = A * B^T, single-product bf16, 16x16x32 MFMA (measured faster
// than 32x32 here). 128x128x32 tile, 4 waves, double-buffered, 1 barrier/it.
// 1D grid 768, XCD swizzle. z==2 epilogue writes V^T [bh][d][n] directly
// (fuses the old vtrans kernel; values bit-identical).
// ---------------------------------------------------------------------------
__global__ __launch_bounds__(256)
void gemm_qkv_kernel(const bf16_t* __restrict__ Ah, const bf16_t* __restrict__ Bh0,
                     bf16_t* __restrict__ Coh0, bf16_t* __restrict__ Vt,
                     int M, int Nn, int Kk) {
    __shared__ __align__(16) bf16_t smem[2][8192];  // 32 KB: A[128x32] | B[128x32]

    const int id = blockIdx.x;
    const int xcd = id & 7;
    const int t = id >> 3;          // 0..95
    const int n0i = t & 7;
    const int u = t >> 3;           // 0..11
    const int z = u >> 2;
    const int m0g = u & 3;
    const int m0 = (m0g * 8 + xcd) * 128;
    const int n0 = n0i * 128;

    const bf16_t* Bh = Bh0 + (size_t)z * Nn * Kk;
    const int tid = threadIdx.x;
    const int wave = tid >> 6, lane = tid & 63, lq = lane >> 4, ln = lane & 15;
    const int wr = wave >> 1, wc = wave & 1;

    // staging: 16 issues (A:8, B:8), 4 per wave
    const bf16_t* g_ptr[4];
    int l_off[4];
#pragma unroll
    for (int q = 0; q < 4; ++q) {
        int e = wave * 4 + q;
        int a = e >> 3, uu = e & 7;
        int C = uu * 64 + lane;
        int r = C >> 2, p = C & 3;
        int c = p ^ ((r >> 1) & 3);           // inverse swizzle on global side
        g_ptr[q] = (a == 0 ? Ah + (size_t)(m0 + r) * Kk
                           : Bh + (size_t)(n0 + r) * Kk) + c * 8;
        l_off[q] = a * 4096 + uu * 512;
    }

    f32x4 acc[4][4] = {};

#pragma unroll
    for (int q = 0; q < 4; ++q)
        async16(g_ptr[q], &smem[0][l_off[q]]);

    const int NIT = Kk / 32;
    for (int j = 0; j < NIT; ++j) {
        __syncthreads();
        if (j + 1 < NIT) {
#pragma unroll
            for (int q = 0; q < 4; ++q)
                async16(g_ptr[q] + (j + 1) * 32, &smem[(j + 1) & 1][l_off[q]]);
        }
        const bf16_t* cur = smem[j & 1];

        bf16x8 ah[4], bh[4];
#pragma unroll
        for (int tt = 0; tt < 4; ++tt) {
            ah[tt] = ldsA32(cur, wr * 64 + tt * 16 + ln, lq);
            bh[tt] = ldsA32(cur + 4096, wc * 64 + tt * 16 + ln, lq);
        }
#pragma unroll
        for (int tm = 0; tm < 4; ++tm)
#pragma unroll
            for (int tn = 0; tn < 4; ++tn)
                acc[tm][tn] = MFMA16(ah[tm], bh[tn], acc[tm][tn]);
    }

    // epilogue. 16x16 C/D: col = lane&15, row = (lane>>4)*4 + reg
    if (z != 2) {
#pragma unroll
        for (int tm = 0; tm < 4; ++tm)
#pragma unroll
            for (int tn = 0; tn < 4; ++tn)
#pragma unroll
                for (int p = 0; p < 4; ++p) {
                    int gm = m0 + wr * 64 + tm * 16 + lq * 4 + p;
                    int gn = n0 + wc * 64 + tn * 16 + ln;
                    Coh0[(size_t)z * M * Nn + (size_t)gm * Nn + gn] =
                        (bf16_t)acc[tm][tn][p];
                }
    } else {
        // V^T: [bh][d][SEQ]; gm -> (b, n), gn -> (h, d); 4 consecutive n per frag
#pragma unroll
        for (int tm = 0; tm < 4; ++tm)
#pragma unroll
            for (int tn = 0; tn < 4; ++tn) {
                int gn = n0 + wc * 64 + tn * 16 + ln;
                int hh = gn >> 6, dd = gn & 63;
                int gm0 = m0 + wr * 64 + tm * 16 + lq * 4;
                int bb = gm0 >> 11, nn = gm0 & 2047;
                bf16x4 v4;
#pragma unroll
                for (int p = 0; p < 4; ++p) v4[p] = (bf16_t)acc[tm][tn][p];
                *(bf16x4*)&Vt[(((size_t)(bb * NHEAD + hh)) * HDIM + dd) * SEQ + nn] = v4;
            }
    }
}

// ---------------------------------------------------------------------------
// Out-proj GEMM: C = A * B^T, single-product bf16, 16x16x32 MFMA, fp32 out.
// 64x128x32 tile, 1D grid 512, XCD swizzle. Double-buffered, 1 barrier/iter.
// ---------------------------------------------------------------------------
__global__ __launch_bounds__(256)
void gemm_out_kernel(const bf16_t* __restrict__ Ah, const bf16_t* __restrict__ Bh,
                     float* __restrict__ Cf, int M, int Nn, int Kk) {
    __shared__ __align__(16) bf16_t smem[2][6144];  // 24 KB: A 64x32 | B 128x32

    const int id = blockIdx.x;
    const int xcd = id & 7;
    const int t = id >> 3;          // 0..63
    const int n0i = t & 7;
    const int m0g = t >> 3;         // 0..7
    const int m0 = (m0g * 8 + xcd) * 64;
    const int n0 = n0i * 128;

    const int tid = threadIdx.x;
    const int wave = tid >> 6, lane = tid & 63, lq = lane >> 4, ln = lane & 15;
    const int wr = wave >> 1, wc = wave & 1;

    // 12 issues (A:4, B:8), 3 per wave
    const bf16_t* g_ptr[3];
    int l_off[3];
#pragma unroll
    for (int q = 0; q < 3; ++q) {
        int e = wave * 3 + q;
        const bf16_t* arr;
        int u, rowbase, lb;
        if (e < 4) { arr = Ah; u = e;     rowbase = m0; lb = 0; }
        else       { arr = Bh; u = e - 4; rowbase = n0; lb = 2048; }
        int r = u * 16 + (lane >> 2), p = lane & 3;
        int c = p ^ ((r >> 1) & 3);
        g_ptr[q] = arr + (size_t)(rowbase + r) * Kk + c * 8;
        l_off[q] = lb + u * 512;
    }

    f32x4 acc[2][4] = {};

#pragma unroll
    for (int q = 0; q < 3; ++q)
        async16(g_ptr[q], &smem[0][l_off[q]]);

    const int NIT = Kk / 32;
    for (int j = 0; j < NIT; ++j) {
        __syncthreads();
        if (j + 1 < NIT) {
#pragma unroll
            for (int q = 0; q < 3; ++q)
                async16(g_ptr[q] + (j + 1) * 32, &smem[(j + 1) & 1][l_off[q]]);
        }
        const bf16_t* cur = smem[j & 1];

        bf16x8 ah[2], bh[4];
#pragma unroll
        for (int tt = 0; tt < 2; ++tt)
            ah[tt] = ldsA32(cur, wr * 32 + tt * 16 + ln, lq);
#pragma unroll
        for (int tt = 0; tt < 4; ++tt)
            bh[tt] = ldsA32(cur + 2048, wc * 64 + tt * 16 + ln, lq);
#pragma unroll
        for (int tm = 0; tm < 2; ++tm)
#pragma unroll
            for (int tn = 0; tn < 4; ++tn)
                acc[tm][tn] = MFMA16(ah[tm], bh[tn], acc[tm][tn]);
    }

#pragma unroll
    for (int tm = 0; tm < 2; ++tm)
#pragma unroll
        for (int tn = 0; tn < 4; ++tn)
#pragma unroll
            for (int p = 0; p < 4; ++p) {
                int gm = m0 + wr * 32 + tm * 16 + lq * 4 + p;
                int gn = n0 + wc * 64 + tn * 16 + ln;
                Cf[(size_t)gm * Nn + gn] = acc[tm][tn][p];
            }
}

// ---------------------------------------------------------------------------
// Flash attention: 512 threads = 2 wave-groups of 4 waves; group g owns keys
// [g*1024, g*1024+1024) with its own double-buffered 64-key K/V tiles.
// XCD-swizzled 1D grid 512. Loop-invariant LDS fragment addresses hoisted
// (xc[] swizzle offsets; staging pointers increment instead of j*step).
// ---------------------------------------------------------------------------
__global__ __launch_bounds__(512, 4)
void attn_kernel(const bf16_t* __restrict__ Qh, const bf16_t* __restrict__ Kh,
                 const bf16_t* __restrict__ Vt, bf16_t* __restrict__ Ch) {
    __shared__ __align__(16) bf16_t smem[2][2][8192];  // [group][buf][K 4096|V 4096]

    const int id = blockIdx.x;
    const int bh = ((id >> 7) << 3) | (id & 7);
    const int qt = (id >> 3) & 15;
    const int b = bh >> 4, h = bh & 15;
    const int q0 = qt * 128;
    const int tid = threadIdx.x;
    const int g = tid >> 8;                    // wave-group 0/1
    const int wv = (tid >> 6) & 3;             // wave within group
    const int lane = tid & 63;
    const int ln32 = lane & 31, hl = lane >> 5;

    // Q fragments: B[q=ln32][k=hl*8+j], chained over hd
    bf16x8 qfh[4];
    {
        size_t qrow = ((size_t)(b * SEQ + q0 + wv * 32 + ln32)) * DMODEL +
                      h * HDIM + hl * 8;
#pragma unroll
        for (int c = 0; c < 4; ++c)
            qfh[c] = *(const bf16x8*)&Qh[qrow + c * 16];
    }

    // hoisted fragment-address terms (loop-invariant): rows kt*32+ln32 have
    // row&7 == ln32&7, so the swizzle xor is kt/dt-independent.
    const int xrow = ln32 * 64;
    int xc[4];
#pragma unroll
    for (int c = 0; c < 4; ++c)
        xc[c] = (((2 * c + hl) ^ (ln32 & 7)) << 3) + xrow;

    // staging: per group 16 issues (K:8, V:8), 4 per wave; keys g*1024 + j*64
    bf16_t* gsm = &smem[g][0][0];
    const bf16_t* g_cur[4];
    int l_off[4];
    size_t g_step[4];
#pragma unroll
    for (int q = 0; q < 4; ++q) {
        int e = wv * 4 + q;
        int a = e >> 3, u = e & 7;
        int r = u * 8 + (lane >> 3), p = lane & 7;
        int c = p ^ (r & 7);                   // inverse swizzle on global side
        if (a == 0) {                          // K tile [64 keys][64 el]
            g_cur[q] = Kh + ((size_t)(b * SEQ + g * 1024 + r)) * DMODEL +
                       h * HDIM + c * 8;
            l_off[q] = u * 512;
            g_step[q] = (size_t)64 * DMODEL;
        } else {                               // V^T tile [64 d][64 keys]
            g_cur[q] = Vt + ((size_t)(bh * HDIM + r)) * SEQ + g * 1024 + c * 8;
            l_off[q] = 4096 + u * 512;
            g_step[q] = 64;
        }
    }

    f32x16 o[2];
#pragma unroll
    for (int dt = 0; dt < 2; ++dt)
#pragma unroll
        for (int r = 0; r < 16; ++r) o[dt][r] = 0.0f;
    float rs = 0.0f;

#pragma unroll
    for (int q = 0; q < 4; ++q) {
        async16(g_cur[q], gsm + l_off[q]);
        g_cur[q] += g_step[q];
    }

    for (int j = 0; j < 16; ++j) {
        __syncthreads();  // buf j&1 DMA landed; reads of buf (j+1)&1 done
        if (j < 15) {
#pragma unroll
            for (int q = 0; q < 4; ++q) {
                async16(g_cur[q], gsm + ((j + 1) & 1) * 8192 + l_off[q]);
                g_cur[q] += g_step[q];
            }
        }
        const bf16_t* Kc = gsm + (j & 1) * 8192;
        const bf16_t* Vc = Kc + 4096;

        bf16x8 pfrag[4];
#pragma unroll
        for (int kt = 0; kt < 2; ++kt) {
            // S^T subtile: D[key = kt*32 + (r&3)+8*(r>>2)+4*hl][q = ln32]
            f32x16 st;
#pragma unroll
            for (int r = 0; r < 16; ++r) st[r] = 0.0f;
#pragma unroll
            for (int c = 0; c < 4; ++c) {
                bf16x8 kh = *(const bf16x8*)&Kc[kt * 2048 + xc[c]];
                st = MFMA32(kh, qfh[c], st);
            }
            float pexp[16];
#pragma unroll
            for (int r = 0; r < 16; ++r) {
                pexp[r] = __builtin_amdgcn_exp2f(st[r]);
                rs += pexp[r];
            }
            // C->B layout: pack bf16 pairs, quad swap with lane^32
#pragma unroll
            for (int s1 = 0; s1 < 2; ++s1) {
                unsigned lo01 = pk(pexp[8 * s1 + 0], pexp[8 * s1 + 1]);
                unsigned lo23 = pk(pexp[8 * s1 + 2], pexp[8 * s1 + 3]);
                unsigned hi01 = pk(pexp[8 * s1 + 4], pexp[8 * s1 + 5]);
                unsigned hi23 = pk(pexp[8 * s1 + 6], pexp[8 * s1 + 7]);
                unsigned sa = hl ? lo01 : hi01;
                unsigned sb = hl ? lo23 : hi23;
                unsigned ra = (unsigned)__shfl_xor((int)sa, 32);
                unsigned rb = (unsigned)__shfl_xor((int)sb, 32);
                union { bf16x8 v; unsigned u[4]; } outv;
                outv.u[0] = hl ? ra : lo01;
                outv.u[1] = hl ? rb : lo23;
                outv.u[2] = hl ? hi01 : ra;
                outv.u[3] = hl ? hi23 : rb;
                pfrag[kt * 2 + s1] = outv.v;
            }
        }
        // O^T += V^T * P over these 64 keys
#pragma unroll
        for (int s = 0; s < 4; ++s) {
            bf16x8 va0 = *(const bf16x8*)&Vc[xc[s]];
            bf16x8 va1 = *(const bf16x8*)&Vc[2048 + xc[s]];
            o[0] = MFMA32(va0, pfrag[s], o[0]);
            o[1] = MFMA32(va1, pfrag[s], o[1]);
        }
    }

    rs += __shfl_xor(rs, 32);  // full group-sum per q-row

    // ---- combine the two groups' partials (additive) ----
    __syncthreads();                                 // (A) j-loop reads done
    float* cbuf = (float*)smem;                      // 64 d x 128 q f32
    float* rbuf = cbuf + 8192;                       // 128 row sums
    if (g == 1) {
#pragma unroll
        for (int dt = 0; dt < 2; ++dt)
#pragma unroll
            for (int r = 0; r < 16; ++r) {
                int d = dt * 32 + (r & 3) + 8 * (r >> 2) + 4 * hl;
                cbuf[d * 128 + wv * 32 + ln32] = o[dt][r];
            }
        if (hl == 0) rbuf[wv * 32 + ln32] = rs;
    }
    __syncthreads();                                 // (B)
    float inv = 0.0f;
    if (g == 0) {
#pragma unroll
        for (int dt = 0; dt < 2; ++dt)
#pragma unroll
            for (int r = 0; r < 16; ++r) {
                int d = dt * 32 + (r & 3) + 8 * (r >> 2) + 4 * hl;
                o[dt][r] += cbuf[d * 128 + wv * 32 + ln32];
            }
        inv = 1.0f / (rs + rbuf[wv * 32 + ln32]);
    }
    __syncthreads();                                 // (C) combine reads done
    float* fbuf = (float*)smem;                      // [dh][wave][32q][33]
    if (g == 0) {
#pragma unroll
        for (int dh = 0; dh < 2; ++dh)
#pragma unroll
            for (int r = 0; r < 16; ++r) {
                int d_loc = (r & 3) + 8 * (r >> 2) + 4 * hl;
                fbuf[dh * 4224 + wv * 1056 + ln32 * 33 + d_loc] = o[dh][r] * inv;
            }
    }
    __syncthreads();                                 // (D)
    // all 8 waves write: wave id = (dh, w)
    {
        int gw = tid >> 6;                           // 0..7
        int dh = gw >> 2, w = gw & 3;
#pragma unroll
        for (int qq = 0; qq < 16; ++qq) {
            int qrow = hl * 16 + qq;
            float v = fbuf[dh * 4224 + w * 1056 + qrow * 33 + ln32];
            size_t gidx = ((size_t)(b * SEQ + q0 + w * 32 + qrow)) * DMODEL +
                          h * HDIM + dh * 32 + ln32;
            Ch[gidx] = (bf16_t)v;
        }
    }
}

// ---------------------------------------------------------------------------
extern "C" void kernel_launch(void* const* d_in, const int* in_sizes, int n_in,
                              void* d_out, int out_size, void* d_ws, size_t ws_size,
                              hipStream_t stream) {
    const float* x  = (const float*)d_in[0];
    const float* Wq = (const float*)d_in[1];
    const float* Wk = (const float*)d_in[2];
    const float* Wv = (const float*)d_in[3];
    const float* Wo = (const float*)d_in[4];
    float* out = (float*)d_out;

    char* ws = (char*)d_ws;
    size_t off = 0;
    auto alloc = [&](size_t bytes) -> bf16_t* {
        bf16_t* p = (bf16_t*)(ws + off);
        off += (bytes + 255) & ~(size_t)255;
        return p;
    };
    const size_t XE = (size_t)MROWS * DMODEL;      // 4,194,304
    const size_t WE = (size_t)DMODEL * DMODEL;     // 1,048,576

    bf16_t* xh  = alloc(XE * 2);
    bf16_t* wh  = alloc(4 * WE * 2);   // q,k,v,o (q/k/v row-reordered, q scaled)
    bf16_t* qnh = alloc(3 * XE * 2);   // Q,K in concat layout (z==2 slab unused)
    bf16_t* vth = alloc(XE * 2);       // V^T per head (written by QKV epilogue)
    bf16_t* ch  = alloc(XE * 2);       // attn output
    (void)ws_size; (void)in_sizes; (void)n_in; (void)out_size;

    // 1. fused splits (hi only)
    split_kernel<<<8192, 256, 0, stream>>>(x, Wq, Wk, Wv, Wo, xh, wh);

    // 2. QKV projections (MFMA16) + fused V-transpose epilogue
    gemm_qkv_kernel<<<768, 256, 0, stream>>>(xh, wh, qnh, vth, MROWS, DMODEL, DMODEL);

    // 3. flash attention (split-K wave groups), XCD-swizzled
    attn_kernel<<<512, 512, 0, stream>>>(qnh, qnh + XE, vth, ch);

    // 4. output projection (MFMA16, single-product) -> fp32 d_out
    gemm_out_kernel<<<512, 256, 0, stream>>>(ch, wh + 3 * WE, out, MROWS, DMODEL, DMODEL);
}